// Round 4
// baseline (59.472 us; speedup 1.0000x reference)
//
#include <hip/hip_runtime.h>
#include <math.h>

#define EPSF 1.1920929e-07f
#define PLANES 8          // x-planes per block; grid = 2*64*64/PLANES = 1024

typedef float f4 __attribute__((ext_vector_type(4)));

__device__ __forceinline__ float sigmoidf_(float v) { return 1.0f / (1.0f + expf(-v)); }

// ---------------------------------------------------------------------------
// Fully fused: each block owns PLANES consecutive (b,c,x) planes of 64x64.
// Redundantly recomputes the tiny MLP (L2-cached weights) once per block,
// then streams PLANES*16 KB in / out. Block 0 also computes the l2 scalar.
// ---------------------------------------------------------------------------
__global__ void __launch_bounds__(256) fused_kernel(
        const float* __restrict__ xin, const float* __restrict__ tab,
        const float* __restrict__ w1,  const float* __restrict__ b1,
        const float* __restrict__ w2,  const float* __restrict__ b2,
        const float* __restrict__ wp,  const float* __restrict__ bp,
        const float* __restrict__ wsg, const float* __restrict__ bsg,
        float* __restrict__ out, int out_last)
{
    __shared__ float emb1[2][32];
    __shared__ float emb2[2][32];
    __shared__ float head[8];
    __shared__ float gys[64];
    __shared__ f4    gz4[16];          // gz as 16 float4s -> ds_read_b128
    __shared__ float pvs[PLANES];
    __shared__ float sh_sh;

    const int blk     = blockIdx.x;            // plane-group index
    const int bc      = blk >> 3;              // 8 groups per (b,c)
    const int xi_base = (blk & 7) * PLANES;
    const int b       = bc >> 6;
    const int c       = bc & 63;
    const int tid     = threadIdx.x;

    // MLP layer 1: emb1[b] = tanh(tab[b] @ w1.T + b1), both batches
    if (tid < 64) {
        int bb = tid >> 5, j = tid & 31;
        float acc = b1[j];
        #pragma unroll
        for (int k = 0; k < 6; ++k) acc += tab[bb * 6 + k] * w1[j * 6 + k];
        emb1[bb][j] = tanhf(acc);
    }
    __syncthreads();

    // MLP layer 2
    if (tid < 64) {
        int bb = tid >> 5, j = tid & 31;
        float acc = b2[j];
        #pragma unroll
        for (int k = 0; k < 32; ++k) acc += emb1[bb][k] * w2[j * 32 + k];
        emb2[bb][j] = tanhf(acc);
    }
    __syncthreads();

    // 8 head values for this (b,c):
    // 0:scale 1:shift 2:mu_a 3:mu_b 4:mu_c   (wp rows q*64+c)
    // 5:sa 6:sb 7:sc                          (ws rows (q-5)*64+c)
    if (tid < 8) {
        const float* W  = (tid < 5) ? wp  : wsg;
        const float* Bv = (tid < 5) ? bp  : bsg;
        int row = ((tid < 5) ? tid : (tid - 5)) * 64 + c;
        float acc = Bv[row];
        #pragma unroll
        for (int k = 0; k < 32; ++k) acc += emb2[b][k] * W[row * 32 + k];
        head[tid] = acc;
    }
    __syncthreads();

    // gaussian tables + plane constants
    if (tid < 64) {
        float m  = tanhf(head[3]) * 32.0f + 31.5f;
        float sg = sigmoidf_(head[6]) * 3.5f + EPSF;
        float d  = ((float)tid - m) / sg;
        gys[tid] = expf(-0.5f * d * d);
    } else if (tid < 128) {
        int i = tid - 64;
        float m  = tanhf(head[4]) * 32.0f + 31.5f;
        float sg = sigmoidf_(head[7]) * 3.5f + EPSF;
        float d  = ((float)i - m) / sg;
        ((float*)gz4)[i] = expf(-0.5f * d * d);
    } else if (tid < 128 + PLANES) {
        int p = tid - 128;
        float m  = tanhf(head[2]) * 32.0f + 31.5f;
        float sg = sigmoidf_(head[5]) * 3.5f + EPSF;
        float d  = ((float)(xi_base + p) - m) / sg;
        pvs[p] = (1.0f - head[0]) * expf(-0.5f * d * d);
        if (p == 0) sh_sh = head[1];
    }

    // block 0 only: l2 = sum of 5 frobenius norms
    if (blk == 0) {
        __shared__ float sq[5][128];
        for (int t = tid; t < 640; t += 256) {
            int q = t / 128, r = t % 128;
            int bb = r >> 6, cc = r & 63;
            const float* W  = (q < 2) ? wp  : wsg;
            const float* Bv = (q < 2) ? bp  : bsg;
            int row = ((q < 2) ? q : (q - 2)) * 64 + cc;
            float acc = Bv[row];
            #pragma unroll
            for (int k = 0; k < 32; ++k) acc += emb2[bb][k] * W[row * 32 + k];
            if (q >= 2) acc = sigmoidf_(acc);
            sq[q][r] = acc * acc;
        }
        __syncthreads();
        if (tid == 0) {
            float tot = 0.0f;
            for (int q = 0; q < 5; ++q) {
                float ssum = 0.0f;
                for (int i = 0; i < 128; ++i) ssum += sq[q][i];
                tot += sqrtf(ssum);
            }
            out[out_last] = tot;
        }
    }
    __syncthreads();

    // streaming: out = pvs[plane]*gy[y]*gz[z] * x + sh  over PLANES planes
    const float sh = sh_sh;
    const f4* x4 = (const f4*)(xin + (size_t)blk * (PLANES * 4096));
    f4*       o4 = (f4*)(out + (size_t)blk * (PLANES * 4096));

    #pragma unroll 8
    for (int k = 0; k < PLANES * 4; ++k) {     // 8192 f4 / 256 threads = 32
        int i4 = k * 256 + tid;
        int pl = i4 >> 10;                     // plane within group
        int w  = i4 & 1023;
        int y  = w >> 4;
        f4 xv = __builtin_nontemporal_load(&x4[i4]);
        f4 gz = gz4[w & 15];
        float m = pvs[pl] * gys[y];
        f4 ov;
        ov.x = fmaf(m * gz.x, xv.x, sh);
        ov.y = fmaf(m * gz.y, xv.y, sh);
        ov.z = fmaf(m * gz.z, xv.z, sh);
        ov.w = fmaf(m * gz.w, xv.w, sh);
        __builtin_nontemporal_store(ov, &o4[i4]);
    }
}

// ---------------------------------------------------------------------------
extern "C" void kernel_launch(void* const* d_in, const int* in_sizes, int n_in,
                              void* d_out, int out_size, void* d_ws, size_t ws_size,
                              hipStream_t stream)
{
    const float* x   = (const float*)d_in[0];
    const float* tab = (const float*)d_in[1];
    const float* w1  = (const float*)d_in[2];
    const float* b1  = (const float*)d_in[3];
    const float* w2  = (const float*)d_in[4];
    const float* b2  = (const float*)d_in[5];
    const float* wp  = (const float*)d_in[6];
    const float* bp  = (const float*)d_in[7];
    const float* wsg = (const float*)d_in[8];
    const float* bsg = (const float*)d_in[9];

    float* out = (float*)d_out;

    fused_kernel<<<(2 * 64 * 64) / PLANES, 256, 0, stream>>>(
        x, tab, w1, b1, w2, b2, wp, bp, wsg, bsg, out, out_size - 1);
}

// Round 5
// 49.621 us; speedup vs baseline: 1.1985x; 1.1985x over previous
//
#include <hip/hip_runtime.h>
#include <math.h>

#define EPSF 1.1920929e-07f

typedef float f4 __attribute__((ext_vector_type(4)));

__device__ __forceinline__ float sigmoidf_(float v) { return 1.0f / (1.0f + expf(-v)); }

// ---------------------------------------------------------------------------
// Fully fused, one (b,c,x) plane of 64x64 per block (8192 blocks, 256 thr).
// Preamble redundantly recomputes the tiny MLP; streaming loop is pure
// NT-load -> packed fma -> NT-store with all gaussian coefficients hoisted
// into 4 f4 registers per thread (z-quad and y-set are loop-invariant).
// ---------------------------------------------------------------------------
__global__ void __launch_bounds__(256) fused_kernel(
        const float* __restrict__ xin, const float* __restrict__ tab,
        const float* __restrict__ w1,  const float* __restrict__ b1,
        const float* __restrict__ w2,  const float* __restrict__ b2,
        const float* __restrict__ wp,  const float* __restrict__ bp,
        const float* __restrict__ wsg, const float* __restrict__ bsg,
        float* __restrict__ out, int out_last)
{
    __shared__ float emb1[2][32];
    __shared__ float emb2[2][32];
    __shared__ float head[8];
    __shared__ float gys[64];
    __shared__ f4    gz4[16];
    __shared__ float pv_sh, sh_sh;

    const int blk = blockIdx.x;        // b*64*64 + c*64 + x
    const int bc  = blk >> 6;
    const int xi  = blk & 63;
    const int b   = bc >> 6;
    const int c   = bc & 63;
    const int tid = threadIdx.x;

    // MLP layer 1: emb1[b] = tanh(tab[b] @ w1.T + b1), both batches
    if (tid < 64) {
        int bb = tid >> 5, j = tid & 31;
        float acc = b1[j];
        #pragma unroll
        for (int k = 0; k < 6; ++k) acc += tab[bb * 6 + k] * w1[j * 6 + k];
        emb1[bb][j] = tanhf(acc);
    }
    __syncthreads();

    // MLP layer 2
    if (tid < 64) {
        int bb = tid >> 5, j = tid & 31;
        float acc = b2[j];
        #pragma unroll
        for (int k = 0; k < 32; ++k) acc += emb1[bb][k] * w2[j * 32 + k];
        emb2[bb][j] = tanhf(acc);
    }
    __syncthreads();

    // 8 head values for this (b,c):
    // 0:scale 1:shift 2:mu_a 3:mu_b 4:mu_c   (wp rows q*64+c)
    // 5:sa 6:sb 7:sc                          (ws rows (q-5)*64+c)
    if (tid < 8) {
        const float* W  = (tid < 5) ? wp  : wsg;
        const float* Bv = (tid < 5) ? bp  : bsg;
        int row = ((tid < 5) ? tid : (tid - 5)) * 64 + c;
        float acc = Bv[row];
        #pragma unroll
        for (int k = 0; k < 32; ++k) acc += emb2[b][k] * W[row * 32 + k];
        head[tid] = acc;
    }
    __syncthreads();

    // gaussian tables + plane constants
    if (tid < 64) {
        float m  = tanhf(head[3]) * 32.0f + 31.5f;
        float sg = sigmoidf_(head[6]) * 3.5f + EPSF;
        float d  = ((float)tid - m) / sg;
        gys[tid] = expf(-0.5f * d * d);
    } else if (tid < 128) {
        int i = tid - 64;
        float m  = tanhf(head[4]) * 32.0f + 31.5f;
        float sg = sigmoidf_(head[7]) * 3.5f + EPSF;
        float d  = ((float)i - m) / sg;
        ((float*)gz4)[i] = expf(-0.5f * d * d);
    } else if (tid == 128) {
        float m  = tanhf(head[2]) * 32.0f + 31.5f;
        float sg = sigmoidf_(head[5]) * 3.5f + EPSF;
        float d  = ((float)xi - m) / sg;
        pv_sh = (1.0f - head[0]) * expf(-0.5f * d * d);
        sh_sh = head[1];
    }

    // block 0 only: l2 = sum of 5 frobenius norms
    if (blk == 0) {
        __shared__ float sq[5][128];
        for (int t = tid; t < 640; t += 256) {
            int q = t / 128, r = t % 128;
            int bb = r >> 6, cc = r & 63;
            const float* W  = (q < 2) ? wp  : wsg;
            const float* Bv = (q < 2) ? bp  : bsg;
            int row = ((q < 2) ? q : (q - 2)) * 64 + cc;
            float acc = Bv[row];
            #pragma unroll
            for (int k = 0; k < 32; ++k) acc += emb2[bb][k] * W[row * 32 + k];
            if (q >= 2) acc = sigmoidf_(acc);
            sq[q][r] = acc * acc;
        }
        __syncthreads();
        if (tid == 0) {
            float tot = 0.0f;
            for (int q = 0; q < 5; ++q) {
                float ssum = 0.0f;
                for (int i = 0; i < 128; ++i) ssum += sq[q][i];
                tot += sqrtf(ssum);
            }
            out[out_last] = tot;
        }
    }
    __syncthreads();

    // ---- streaming: hoist all coefficients to registers ----
    // thread (tid) covers f4 indices tid + 256k, k=0..3:
    //   z-quad  = (tid & 15)*4            (loop-invariant)
    //   y       = (tid >> 4) + 16k        (4 values)
    const float pv = pv_sh;
    const float sh = sh_sh;
    const int   yb = tid >> 4;
    const f4    vz = gz4[tid & 15];
    const f4 w0 = vz * (pv * gys[yb]);
    const f4 w1_ = vz * (pv * gys[yb + 16]);
    const f4 w2_ = vz * (pv * gys[yb + 32]);
    const f4 w3_ = vz * (pv * gys[yb + 48]);
    const f4 shv = {sh, sh, sh, sh};

    const f4* x4 = (const f4*)(xin + (size_t)blk * 4096);
    f4*       o4 = (f4*)(out + (size_t)blk * 4096);

    f4 x0 = __builtin_nontemporal_load(&x4[tid]);
    f4 x1 = __builtin_nontemporal_load(&x4[tid + 256]);
    f4 x2 = __builtin_nontemporal_load(&x4[tid + 512]);
    f4 x3 = __builtin_nontemporal_load(&x4[tid + 768]);

    __builtin_nontemporal_store(w0  * x0 + shv, &o4[tid]);
    __builtin_nontemporal_store(w1_ * x1 + shv, &o4[tid + 256]);
    __builtin_nontemporal_store(w2_ * x2 + shv, &o4[tid + 512]);
    __builtin_nontemporal_store(w3_ * x3 + shv, &o4[tid + 768]);
}

// ---------------------------------------------------------------------------
extern "C" void kernel_launch(void* const* d_in, const int* in_sizes, int n_in,
                              void* d_out, int out_size, void* d_ws, size_t ws_size,
                              hipStream_t stream)
{
    const float* x   = (const float*)d_in[0];
    const float* tab = (const float*)d_in[1];
    const float* w1  = (const float*)d_in[2];
    const float* b1  = (const float*)d_in[3];
    const float* w2  = (const float*)d_in[4];
    const float* b2  = (const float*)d_in[5];
    const float* wp  = (const float*)d_in[6];
    const float* bp  = (const float*)d_in[7];
    const float* wsg = (const float*)d_in[8];
    const float* bsg = (const float*)d_in[9];

    float* out = (float*)d_out;

    fused_kernel<<<2 * 64 * 64, 256, 0, stream>>>(
        x, tab, w1, b1, w2, b2, wp, bp, wsg, bsg, out, out_size - 1);
}